// Round 14
// baseline (212.530 us; speedup 1.0000x reference)
//
#include <hip/hip_runtime.h>
#include <hip/hip_bf16.h>

#define S_ 2048
#define DH_ 64
#define NE_ 8388608  // 8192*1024 elems per activation tensor

using f32x4  = __attribute__((ext_vector_type(4))) float;
using bf16x8 = __attribute__((ext_vector_type(8))) __bf16;
using bf16x4 = __attribute__((ext_vector_type(4))) __bf16;

__device__ __forceinline__ unsigned int f2bf(float f) {
    union { float f; unsigned int u; } x; x.f = f;
    return (x.u + 0x7FFFu + ((x.u >> 16) & 1u)) >> 16;  // RNE
}

// async global->LDS, 16B per lane. LDS dest = wave-uniform base + lane*16.
__device__ __forceinline__ void gl_lds16(const unsigned short* g, unsigned short* l) {
    __builtin_amdgcn_global_load_lds(
        (const __attribute__((address_space(1))) unsigned int*)(const void*)g,
        (__attribute__((address_space(3))) unsigned int*)(void*)l,
        16, 0, 0);
}

// ---------------- fused fp32->bf16 convert: 4 weights + 3 activations ----------------
__global__ __launch_bounds__(256) void cvt_all(const float* __restrict__ w0, const float* __restrict__ w1,
                                               const float* __restrict__ w2, const float* __restrict__ w3,
                                               const float* __restrict__ a0, const float* __restrict__ a1,
                                               const float* __restrict__ a2,
                                               unsigned short* __restrict__ wout,
                                               unsigned short* __restrict__ aout) {
    const int y = blockIdx.y;
    const float* src;
    unsigned short* dst;
    if (y < 4) {
        if (blockIdx.x >= 1024) return;
        src = y == 0 ? w0 : y == 1 ? w1 : y == 2 ? w2 : w3;
        dst = wout + (size_t)y * 1048576;
    } else {
        src = y == 4 ? a0 : y == 5 ? a1 : a2;
        dst = aout + (size_t)(y - 4) * NE_;
    }
    int i = (blockIdx.x * 256 + threadIdx.x) * 4;
    float4 v = *(const float4*)&src[i];
    ushort4 h;
    h.x = f2bf(v.x); h.y = f2bf(v.y); h.z = f2bf(v.z); h.w = f2bf(v.w);
    *(ushort4*)&dst[i] = h;
}

// ---------------- 256x128-tile 2-phase GEMM (qkv8 schedule transform) ----------------
// 8 waves (4M x 2N), per-wave 64x64, BK=64, 16 K-tiles. LDS 96KB: A 2buf x 256x64,
// B 2buf x 128x64. Per K-tile: phaseA {B-frags + A m0,m1 || STG A(t+1) x2} barrier/
// lgkm/16 MFMA; phaseB {A m2,m3 || STG B(t+2), vmcnt(2)} barrier/lgkm/16 MFMA.
// vmcnt(2) retires exactly {A(t+1),B(t+1)}, leaves B(t+2) in flight. Slot-XOR swizzle
// (r9-verified): LDS slot s of row r holds global slot s^(r&7).
// OMODE 0: fused QKV (grid 768 = 3 exact rounds; range = by>>3, scatter per range).
// OMODE 1: fp32 out = A @ Bw^T + bias (grid 256 = 1 exact round).
template<int OMODE>
__global__ __launch_bounds__(512, 2) void gemm2ph(const unsigned short* __restrict__ Aact,
                                                  const unsigned short* __restrict__ Bw,
                                                  const float* __restrict__ bq,
                                                  const float* __restrict__ bk,
                                                  const float* __restrict__ bvv,
                                                  unsigned short* __restrict__ Qp,
                                                  unsigned short* __restrict__ Kp,
                                                  unsigned short* __restrict__ VTp,
                                                  float* __restrict__ Cf,
                                                  float scq)
{
    __shared__ unsigned short lds[49152];   // elems: A [0,32768), B [32768,49152)
    unsigned short* ldsA = lds;
    unsigned short* ldsB = lds + 32768;

    // bijective XCD swizzle (nwg % 8 == 0)
    const int q8 = gridDim.x >> 3;
    const int lid = (blockIdx.x & 7) * q8 + (blockIdx.x >> 3);
    const int bx = lid & 31;        // 32 row tiles (M=8192/256)
    const int by = lid >> 5;        // col tiles of 128

    const unsigned short* Ag = (OMODE == 0) ? Aact + (size_t)(by >> 3) * NE_ : Aact;
    const int arow0 = bx * 256;
    const int brow0 = by * 128;

    const int tid = threadIdx.x, lane = tid & 63, wid = tid >> 6;
    const int fr = lane & 15, fg = lane >> 4;
    const int wid_m = wid >> 1, wid_n = wid & 1;

    // staging maps: lds linear dest, slot-XOR pre-swizzled global source (128 rows/STG)
    const int srcRow0 = wid * 16 + (lane >> 3);
    const int scolS = ((lane & 7) ^ ((lane >> 3) & 7)) << 3;

    auto STG = [&](int ldsOff, const unsigned short* g, int grow, int kk) {
        const unsigned short* s0 = g + (size_t)(grow + srcRow0) * 1024 + kk + scolS;
        gl_lds16(s0, lds + ldsOff + wid * 1024 + lane * 8);
        gl_lds16(s0 + 8 * 1024, lds + ldsOff + wid * 1024 + 512 + lane * 8);
    };

    // ds_read bases: slot (ks*4+fg) ^ (fr&7)
    const int fx = fr & 7;
    const int vA0 = wid_m * 4096 + fr * 64 + ((fg ^ fx) << 3);
    const int vA1 = wid_m * 4096 + fr * 64 + (((4 | fg) ^ fx) << 3);
    const int vB0 = wid_n * 4096 + fr * 64 + ((fg ^ fx) << 3);
    const int vB1 = wid_n * 4096 + fr * 64 + (((4 | fg) ^ fx) << 3);

    f32x4 acc[4][4] = {};

    // prologue: A-T0 -> Ab0, B-T0 -> Bb0, B-T1 -> Bb1; wait all but B-T1
    STG(0,            Ag, arow0,       0);
    STG(8192,         Ag, arow0 + 128, 0);
    STG(32768,        Bw, brow0,       0);
    STG(32768 + 8192, Bw, brow0,      64);
    asm volatile("s_waitcnt vmcnt(2)" ::: "memory");
    __builtin_amdgcn_s_barrier();

    for (int t = 0; t < 16; ++t) {
        const int cur = t & 1;
        const int ldA = cur * 16384, ldB = cur * 8192;

        // ---- phase A: B-frags + A m-frags 0,1; stage A(t+1) ----
        bf16x8 bfr[4][2], af[2][2];
        #pragma unroll
        for (int j = 0; j < 4; ++j) {
            bfr[j][0] = *(const bf16x8*)&ldsB[ldB + vB0 + j * 1024];
            bfr[j][1] = *(const bf16x8*)&ldsB[ldB + vB1 + j * 1024];
        }
        #pragma unroll
        for (int i = 0; i < 2; ++i) {
            af[i][0] = *(const bf16x8*)&ldsA[ldA + vA0 + i * 1024];
            af[i][1] = *(const bf16x8*)&ldsA[ldA + vA1 + i * 1024];
        }
        {
            const int ka = ((t + 1) & 15) * 64;
            STG((cur ^ 1) * 16384,        Ag, arow0,       ka);
            STG((cur ^ 1) * 16384 + 8192, Ag, arow0 + 128, ka);
        }
        __builtin_amdgcn_s_barrier();
        asm volatile("s_waitcnt lgkmcnt(0)" ::: "memory");
        __builtin_amdgcn_s_setprio(1);
        #pragma unroll
        for (int i = 0; i < 2; ++i)
            #pragma unroll
            for (int j = 0; j < 4; ++j) {
                acc[i][j] = __builtin_amdgcn_mfma_f32_16x16x32_bf16(af[i][0], bfr[j][0], acc[i][j], 0, 0, 0);
                acc[i][j] = __builtin_amdgcn_mfma_f32_16x16x32_bf16(af[i][1], bfr[j][1], acc[i][j], 0, 0, 0);
            }
        __builtin_amdgcn_s_setprio(0);
        __builtin_amdgcn_s_barrier();

        // ---- phase B: A m-frags 2,3; stage B(t+2); counted vmcnt ----
        bf16x8 af2[2][2];
        #pragma unroll
        for (int i = 0; i < 2; ++i) {
            af2[i][0] = *(const bf16x8*)&ldsA[ldA + vA0 + (2 + i) * 1024];
            af2[i][1] = *(const bf16x8*)&ldsA[ldA + vA1 + (2 + i) * 1024];
        }
        {
            const int kb = ((t + 2) & 15) * 64;
            STG(32768 + ldB, Bw, brow0, kb);
        }
        asm volatile("s_waitcnt vmcnt(2)" ::: "memory");
        __builtin_amdgcn_s_barrier();
        asm volatile("s_waitcnt lgkmcnt(0)" ::: "memory");
        __builtin_amdgcn_s_setprio(1);
        #pragma unroll
        for (int i = 0; i < 2; ++i)
            #pragma unroll
            for (int j = 0; j < 4; ++j) {
                acc[2 + i][j] = __builtin_amdgcn_mfma_f32_16x16x32_bf16(af2[i][0], bfr[j][0], acc[2 + i][j], 0, 0, 0);
                acc[2 + i][j] = __builtin_amdgcn_mfma_f32_16x16x32_bf16(af2[i][1], bfr[j][1], acc[2 + i][j], 0, 0, 0);
            }
        __builtin_amdgcn_s_setprio(0);
        __builtin_amdgcn_s_barrier();
    }
    asm volatile("s_waitcnt vmcnt(0)" ::: "memory");  // drain dummy prefetches

    // epilogue: wave owns rows [wid_m*64,+64) x cols [wid_n*64,+64) of the 256x128 tile
    const int row00 = bx * 256 + wid_m * 64;
    if (OMODE == 1) {
        const int col0 = by * 128 + wid_n * 64;
        #pragma unroll
        for (int i = 0; i < 4; ++i)
            #pragma unroll
            for (int j = 0; j < 4; ++j) {
                int c = col0 + j * 16 + fr;
                float bv = bq[c];   // bo passed via bq
                #pragma unroll
                for (int r = 0; r < 4; ++r) {
                    int row = row00 + i * 16 + fg * 4 + r;
                    Cf[(size_t)row * 1024 + c] = acc[i][j][r] + bv;
                }
            }
    } else {
        const int range = by >> 3;      // 0:Q 1:K 2:V
        const float os = range == 0 ? scq : 1.0f;
        const float* bp = range == 0 ? bq : range == 1 ? bk : bvv;
        unsigned short* OP = range == 0 ? Qp : Kp;
        const int colbase = (by & 7) * 128 + wid_n * 64;
        #pragma unroll
        for (int i = 0; i < 4; ++i)
            #pragma unroll
            for (int j = 0; j < 4; ++j) {
                int colr = colbase + j * 16 + fr;
                float bias = bp[colr];
                int h = colr >> 6, dh = colr & 63;
                if (range == 2) {
                    int row = row00 + i * 16 + fg * 4;
                    int b = row >> 11, s = row & 2047;
                    unsigned int w0 = f2bf(acc[i][j][0] + bias) | (f2bf(acc[i][j][1] + bias) << 16);
                    unsigned int w1 = f2bf(acc[i][j][2] + bias) | (f2bf(acc[i][j][3] + bias) << 16);
                    *(uint2*)&VTp[((size_t)((b << 4) + h) * 64 + dh) * 2048 + s] = make_uint2(w0, w1);
                } else {
                    #pragma unroll
                    for (int r = 0; r < 4; ++r) {
                        int row = row00 + i * 16 + fg * 4 + r;
                        int b = row >> 11, s = row & 2047;
                        OP[((((b << 4) + h) * 2048 + s) << 6) + dh] =
                            (unsigned short)f2bf((acc[i][j][r] + bias) * os);
                    }
                }
            }
    }
}

// ---------------- Flash attention v5 (r5 measured-best, unchanged) ----------------
__global__ __launch_bounds__(512, 4) void attn_fwd5(const unsigned short* __restrict__ Qp,
                                                    const unsigned short* __restrict__ Kp,
                                                    const unsigned short* __restrict__ VTg,
                                                    unsigned short* __restrict__ ctx)
{
    __shared__ unsigned short Ks[64][68];
    __shared__ unsigned short Vt[64][68];
    __shared__ unsigned short Ps[8][16][68];

    const int lin = blockIdx.x;
    const int xcd = lin & 7;
    const int w = lin >> 3;
    const int bh = xcd * 8 + (w & 7);     // XCD owns 8 complete heads
    const int j = 15 - (w >> 3);          // heavy blocks first
    const int b = bh >> 4, h = bh & 15;
    const int tid = threadIdx.x, lane = tid & 63, wid = tid >> 6;
    const int fr = lane & 15, fg = lane >> 4;

    const unsigned short* Qh  = Qp  + (size_t)bh * (S_ * DH_);
    const unsigned short* Kh  = Kp  + (size_t)bh * (S_ * DH_);
    const unsigned short* VTh = VTg + (size_t)bh * (DH_ * S_);

    const int srow = tid >> 3;
    const int scol = (tid & 7) * 8;

    bf16x8 ones;
    #pragma unroll
    for (int i = 0; i < 8; ++i) ones[i] = (__bf16)1.0f;

    const int q0 = j * 128;
    const int ntiles = 2 * (j + 1);
    const int rbase = q0 + wid * 16;
    const int qg = rbase + fr;

    bf16x8 qf[2];
    #pragma unroll
    for (int ks = 0; ks < 2; ++ks)
        qf[ks] = *(const bf16x8*)&Qh[(size_t)qg * 64 + ks * 32 + 8 * fg];

    f32x4 oacc[4] = {};
    float m_run = -3.0e38f, l_run = 0.0f;

    int4 kreg = *(const int4*)&Kh[(size_t)srow * 64 + scol];
    int4 vreg = *(const int4*)&VTh[(size_t)srow * 2048 + scol];

    for (int kt = 0; kt < ntiles; ++kt) {
        const int kv0 = kt * 64;
        __syncthreads();
        *(int4*)&Ks[srow][scol] = kreg;
        *(int4*)&Vt[srow][scol] = vreg;
        if (kt + 1 < ntiles) {
            const int kv1 = kv0 + 64;
            kreg = *(const int4*)&Kh[(size_t)(kv1 + srow) * 64 + scol];
            vreg = *(const int4*)&VTh[(size_t)srow * 2048 + kv1 + scol];
        }
        __syncthreads();

        if (kv0 > rbase + 15) continue;

        f32x4 sacc[4] = {};
        #pragma unroll
        for (int nt = 0; nt < 4; ++nt)
            #pragma unroll
            for (int ks = 0; ks < 2; ++ks) {
                bf16x8 kf = *(const bf16x8*)&Ks[nt * 16 + fr][ks * 32 + 8 * fg];
                sacc[nt] = __builtin_amdgcn_mfma_f32_16x16x32_bf16(kf, qf[ks], sacc[nt], 0, 0, 0);
            }

        if (kv0 + 63 > rbase) {
            const int kbase = kv0 + fg * 4;
            #pragma unroll
            for (int nt = 0; nt < 4; ++nt)
                #pragma unroll
                for (int r = 0; r < 4; ++r)
                    if (kbase + nt * 16 + r > qg) sacc[nt][r] = -3.0e38f;
        }

        float vm = sacc[0][0];
        #pragma unroll
        for (int nt = 0; nt < 4; ++nt)
            #pragma unroll
            for (int r = 0; r < 4; ++r) vm = fmaxf(vm, sacc[nt][r]);
        vm = fmaxf(vm, __shfl_xor(vm, 16));
        vm = fmaxf(vm, __shfl_xor(vm, 32));

        if (!__all(vm - m_run <= 8.0f)) {
            const float mn = fmaxf(m_run, vm);
            const float alpha = exp2f(m_run - mn);
            m_run = mn;
            l_run *= alpha;
            #pragma unroll
            for (int dt = 0; dt < 4; ++dt)
                #pragma unroll
                for (int r = 0; r < 4; ++r) oacc[dt][r] *= alpha;
        }

        #pragma unroll
        for (int nt = 0; nt < 4; ++nt) {
            bf16x4 t;
            t[0] = (__bf16)exp2f(sacc[nt][0] - m_run);
            t[1] = (__bf16)exp2f(sacc[nt][1] - m_run);
            t[2] = (__bf16)exp2f(sacc[nt][2] - m_run);
            t[3] = (__bf16)exp2f(sacc[nt][3] - m_run);
            *(bf16x4*)&Ps[wid][fr][nt * 16 + fg * 4] = t;
        }
        asm volatile("s_waitcnt lgkmcnt(0)" ::: "memory");

        bf16x8 pb[2];
        #pragma unroll
        for (int ks = 0; ks < 2; ++ks)
            pb[ks] = *(const bf16x8*)&Ps[wid][fr][ks * 32 + 8 * fg];

        f32x4 racc = {};
        #pragma unroll
        for (int ks = 0; ks < 2; ++ks)
            racc = __builtin_amdgcn_mfma_f32_16x16x32_bf16(ones, pb[ks], racc, 0, 0, 0);
        #pragma unroll
        for (int dt = 0; dt < 4; ++dt)
            #pragma unroll
            for (int ks = 0; ks < 2; ++ks) {
                bf16x8 vf = *(const bf16x8*)&Vt[dt * 16 + fr][ks * 32 + 8 * fg];
                oacc[dt] = __builtin_amdgcn_mfma_f32_16x16x32_bf16(vf, pb[ks], oacc[dt], 0, 0, 0);
            }
        l_run += racc[0];
    }

    const float linv = 1.0f / l_run;
    unsigned short* cb = &ctx[(size_t)(b * 2048 + qg) * 1024 + h * 64];
    #pragma unroll
    for (int dt = 0; dt < 4; ++dt) {
        unsigned int w0 = f2bf(oacc[dt][0] * linv) | (f2bf(oacc[dt][1] * linv) << 16);
        unsigned int w1 = f2bf(oacc[dt][2] * linv) | (f2bf(oacc[dt][3] * linv) << 16);
        *(uint2*)&cb[dt * 16 + fg * 4] = make_uint2(w0, w1);
    }
}

extern "C" void kernel_launch(void* const* d_in, const int* in_sizes, int n_in,
                              void* d_out, int out_size, void* d_ws, size_t ws_size,
                              hipStream_t stream)
{
    const float* q  = (const float*)d_in[0];
    const float* k  = (const float*)d_in[1];
    const float* v  = (const float*)d_in[2];
    const float* Wq = (const float*)d_in[4];
    const float* bq = (const float*)d_in[5];
    const float* Wk = (const float*)d_in[6];
    const float* bk = (const float*)d_in[7];
    const float* Wv = (const float*)d_in[8];
    const float* bv = (const float*)d_in[9];
    const float* Wo = (const float*)d_in[10];
    const float* bo = (const float*)d_in[11];
    float* out = (float*)d_out;

    unsigned short* Wcat = (unsigned short*)d_ws;          // [Wq;Wk;Wv;Wo] bf16
    unsigned short* actb = Wcat + 4 * 1048576;             // [qb;kb;vb] bf16
    unsigned short* Qp   = actb + 3 * (size_t)NE_;
    unsigned short* Kp   = Qp + NE_;
    unsigned short* VTp  = Kp + NE_;                       // V in [B,H,DH,S]
    unsigned short* Ctx  = VTp + NE_;

    const float SCQ = 0.045084220027780106f;  // log2(e)/sqrt(D)

    dim3 blk(256);
    cvt_all<<<dim3(8192, 7), blk, 0, stream>>>(Wq, Wk, Wv, Wo, q, k, v, Wcat, actb);

    gemm2ph<0><<<dim3(768), dim3(512), 0, stream>>>(actb, Wcat, bq, bk, bv,
                                                    Qp, Kp, VTp, nullptr, SCQ);

    attn_fwd5<<<dim3(1024), dim3(512), 0, stream>>>(Qp, Kp, VTp, Ctx);

    gemm2ph<1><<<dim3(256), dim3(512), 0, stream>>>(Ctx, Wcat + 3 * 1048576, bo,
                                                    nullptr, nullptr, nullptr, nullptr,
                                                    nullptr, out, 1.0f);
}

// Round 15
// 204.022 us; speedup vs baseline: 1.0417x; 1.0417x over previous
//
#include <hip/hip_runtime.h>
#include <hip/hip_bf16.h>

#define S_ 2048
#define DH_ 64
#define NE_ 8388608  // 8192*1024 elems per activation tensor

using f32x4  = __attribute__((ext_vector_type(4))) float;
using bf16x8 = __attribute__((ext_vector_type(8))) __bf16;
using bf16x4 = __attribute__((ext_vector_type(4))) __bf16;

__device__ __forceinline__ unsigned int f2bf(float f) {
    union { float f; unsigned int u; } x; x.f = f;
    return (x.u + 0x7FFFu + ((x.u >> 16) & 1u)) >> 16;  // RNE
}

// async global->LDS, 16B per lane. LDS dest = wave-uniform base + lane*16.
__device__ __forceinline__ void gl_lds16(const unsigned short* g, unsigned short* l) {
    __builtin_amdgcn_global_load_lds(
        (const __attribute__((address_space(1))) unsigned int*)(const void*)g,
        (__attribute__((address_space(3))) unsigned int*)(void*)l,
        16, 0, 0);
}

// ---------------- fused fp32->bf16 convert: 4 weights + 3 activations ----------------
__global__ __launch_bounds__(256) void cvt_all(const float* __restrict__ w0, const float* __restrict__ w1,
                                               const float* __restrict__ w2, const float* __restrict__ w3,
                                               const float* __restrict__ a0, const float* __restrict__ a1,
                                               const float* __restrict__ a2,
                                               unsigned short* __restrict__ wout,
                                               unsigned short* __restrict__ aout) {
    const int y = blockIdx.y;
    const float* src;
    unsigned short* dst;
    if (y < 4) {
        if (blockIdx.x >= 1024) return;
        src = y == 0 ? w0 : y == 1 ? w1 : y == 2 ? w2 : w3;
        dst = wout + (size_t)y * 1048576;
    } else {
        src = y == 4 ? a0 : y == 5 ? a1 : a2;
        dst = aout + (size_t)(y - 4) * NE_;
    }
    int i = (blockIdx.x * 256 + threadIdx.x) * 4;
    float4 v = *(const float4*)&src[i];
    ushort4 h;
    h.x = f2bf(v.x); h.y = f2bf(v.y); h.z = f2bf(v.z); h.w = f2bf(v.w);
    *(ushort4*)&dst[i] = h;
}

// ---------------- fused QKV projection: 256^2 tile, 8-phase pipelined (r9 measured-best) ----------------
__global__ __launch_bounds__(512, 2) void gemm_qkv8(const unsigned short* __restrict__ actb,
                                                    const unsigned short* __restrict__ Wcat,
                                                    const float* __restrict__ bq,
                                                    const float* __restrict__ bk,
                                                    const float* __restrict__ bvv,
                                                    unsigned short* __restrict__ Qp,
                                                    unsigned short* __restrict__ Kp,
                                                    unsigned short* __restrict__ VTp,
                                                    float scq)
{
    __shared__ unsigned short lds[65536];   // elems: A [0,32768), B [32768,65536)
    unsigned short* ldsA = lds;
    unsigned short* ldsB = lds + 32768;

    // bijective XCD swizzle: nwg=384, q=48, r=0
    const int orig = blockIdx.x;
    const int lid = (orig & 7) * 48 + (orig >> 3);
    const int bx = lid & 31;        // 32 row tiles
    const int by = lid >> 5;        // 12 col tiles
    const int range = by >> 2;      // 0:Q 1:K 2:V
    const unsigned short* Aact = actb + (size_t)range * NE_;

    const int tid = threadIdx.x, lane = tid & 63, wid = tid >> 6;
    const int fr = lane & 15, fg = lane >> 4;
    const int wid_m = wid >> 2, wid_n = wid & 3;

    // staging maps (per-lane): lds linear dest, slot-XOR pre-swizzled global source
    const int srcRow0 = wid * 16 + (lane >> 3);                       // u=0; u=1: +8
    const int scolS = ((lane & 7) ^ ((lane >> 3) & 7)) << 3;          // elems

    auto STG = [&](int ldsRegion, const unsigned short* g, int grow, int kk) {
        const unsigned short* s0 = g + (size_t)(grow + srcRow0) * 1024 + kk + scolS;
        gl_lds16(s0, lds + ldsRegion + wid * 1024 + lane * 8);
        gl_lds16(s0 + 8 * 1024, lds + ldsRegion + wid * 1024 + 512 + lane * 8);
    };

    // ds_read bases (elems), slot-XOR swizzle: slot (ks*4+fg) ^ (fr&7)
    const int fx = fr & 7;
    const int vA0 = wid_m * 8192 + fr * 64 + ((fg ^ fx) << 3);
    const int vA1 = wid_m * 8192 + fr * 64 + (((4 | fg) ^ fx) << 3);
    const int vBr = (wid_n & 1) * 4096 + (wid_n >> 1) * 8192 + fr * 64;
    const int vB0 = vBr + ((fg ^ fx) << 3);
    const int vB1 = vBr + (((4 | fg) ^ fx) << 3);

    f32x4 acc[8][4] = {};
    bf16x8 bfr[4][2];

    // prologue: A-buf0<-T0 (h0,h1), B-buf0<-T0, B-buf1<-T1; retire first 8, keep 4
    STG(0,          Aact, bx * 256,       0);
    STG(8192,       Aact, bx * 256 + 128, 0);
    STG(32768,      Wcat, by * 256,       0);
    STG(32768+8192, Wcat, by * 256 + 128, 0);
    STG(32768+16384,       Wcat, by * 256,       64);
    STG(32768+16384+8192,  Wcat, by * 256 + 128,  64);
    asm volatile("s_waitcnt vmcnt(4)" ::: "memory");
    __builtin_amdgcn_s_barrier();

#define KTILE(BUF, ABUF, TA, BBUF, TB)                                              \
  {                                                                                 \
    _Pragma("unroll")                                                               \
    for (int q = 0; q < 4; ++q) {                                                   \
      if (q == 0) {                                                                 \
        _Pragma("unroll")                                                           \
        for (int j = 0; j < 4; ++j) {                                               \
          bfr[j][0] = *(const bf16x8*)&ldsB[(BUF)*16384 + vB0 + j*1024];            \
          bfr[j][1] = *(const bf16x8*)&ldsB[(BUF)*16384 + vB1 + j*1024];            \
        }                                                                           \
      }                                                                             \
      bf16x8 af[2][2];                                                              \
      _Pragma("unroll")                                                             \
      for (int i2 = 0; i2 < 2; ++i2) {                                              \
        af[i2][0] = *(const bf16x8*)&ldsA[(BUF)*16384 + vA0 + (q*2+i2)*1024];       \
        af[i2][1] = *(const bf16x8*)&ldsA[(BUF)*16384 + vA1 + (q*2+i2)*1024];       \
      }                                                                             \
      if (q == 0) STG((ABUF)*16384,        Aact, bx*256,       ((TA)&15)*64);       \
      if (q == 1) STG((ABUF)*16384 + 8192, Aact, bx*256 + 128, ((TA)&15)*64);       \
      if (q == 2) STG(32768 + (BBUF)*16384,        Wcat, by*256,       ((TB)&15)*64); \
      if (q == 3) { STG(32768 + (BBUF)*16384 + 8192, Wcat, by*256 + 128, ((TB)&15)*64); \
                    asm volatile("s_waitcnt vmcnt(4)" ::: "memory"); }              \
      __builtin_amdgcn_s_barrier();                                                 \
      asm volatile("s_waitcnt lgkmcnt(0)" ::: "memory");                            \
      __builtin_amdgcn_s_setprio(1);                                                \
      _Pragma("unroll")                                                             \
      for (int i2 = 0; i2 < 2; ++i2)                                                \
        _Pragma("unroll")                                                           \
        for (int j = 0; j < 4; ++j) {                                               \
          acc[q*2+i2][j] = __builtin_amdgcn_mfma_f32_16x16x32_bf16(af[i2][0], bfr[j][0], acc[q*2+i2][j], 0, 0, 0); \
          acc[q*2+i2][j] = __builtin_amdgcn_mfma_f32_16x16x32_bf16(af[i2][1], bfr[j][1], acc[q*2+i2][j], 0, 0, 0); \
        }                                                                           \
      __builtin_amdgcn_s_setprio(0);                                                \
      __builtin_amdgcn_s_barrier();                                                 \
    }                                                                               \
  }

    for (int it = 0; it < 8; ++it) {
        const int t0 = 2 * it;
        KTILE(0, 1, t0 + 1, 0, t0 + 2);   // phases 1-4: read buf0; stage A-buf1<-T1, B-buf0<-T2
        KTILE(1, 0, t0 + 2, 1, t0 + 3);   // phases 5-8: read buf1; stage A-buf0<-T2, B-buf1<-T3
    }
#undef KTILE

    asm volatile("s_waitcnt vmcnt(0)" ::: "memory");  // drain dummy prefetches before exit

    // epilogue: wave owns rows [wid_m*128,+128) x cols [wid_n*64,+64) of the 256^2 tile
    const float* bp = range == 0 ? bq : range == 1 ? bk : bvv;
    const float os = range == 0 ? scq : 1.0f;
    unsigned short* OP = range == 0 ? Qp : Kp;
    const int row00 = bx * 256 + wid_m * 128;
    const int col0r = (by & 3) * 256 + wid_n * 64;   // within range [0,1024)

    #pragma unroll
    for (int i = 0; i < 8; ++i) {
        #pragma unroll
        for (int j = 0; j < 4; ++j) {
            int colr = col0r + j * 16 + fr;
            float bias = bp[colr];
            int h = colr >> 6, dh = colr & 63;
            if (range == 2) {
                int row = row00 + i * 16 + fg * 4;
                int b = row >> 11, s = row & 2047;
                unsigned int w0 = f2bf(acc[i][j][0] + bias) | (f2bf(acc[i][j][1] + bias) << 16);
                unsigned int w1 = f2bf(acc[i][j][2] + bias) | (f2bf(acc[i][j][3] + bias) << 16);
                *(uint2*)&VTp[((size_t)((b << 4) + h) * 64 + dh) * 2048 + s] = make_uint2(w0, w1);
            } else {
                #pragma unroll
                for (int r = 0; r < 4; ++r) {
                    int row = row00 + i * 16 + fg * 4 + r;
                    int b = row >> 11, s = row & 2047;
                    OP[((((b << 4) + h) * 2048 + s) << 6) + dh] =
                        (unsigned short)f2bf((acc[i][j][r] + bias) * os);
                }
            }
        }
    }
}

// ---------------- output projection: 256x128-tile 2-phase (r14 winner for gemm_o) ----------------
// grid 256 = exact 1 round. A (Ctx, 16MB) is L3-resident so 8-way col re-read is free.
__global__ __launch_bounds__(512, 2) void gemm_o2(const unsigned short* __restrict__ Aact,
                                                  const unsigned short* __restrict__ Bw,
                                                  const float* __restrict__ bias,
                                                  float* __restrict__ Cf)
{
    __shared__ unsigned short lds[49152];   // elems: A [0,32768), B [32768,49152)
    unsigned short* ldsA = lds;
    unsigned short* ldsB = lds + 32768;

    const int q8 = gridDim.x >> 3;
    const int lid = (blockIdx.x & 7) * q8 + (blockIdx.x >> 3);
    const int bx = lid & 31;
    const int by = lid >> 5;

    const int arow0 = bx * 256;
    const int brow0 = by * 128;

    const int tid = threadIdx.x, lane = tid & 63, wid = tid >> 6;
    const int fr = lane & 15, fg = lane >> 4;
    const int wid_m = wid >> 1, wid_n = wid & 1;

    const int srcRow0 = wid * 16 + (lane >> 3);
    const int scolS = ((lane & 7) ^ ((lane >> 3) & 7)) << 3;

    auto STG = [&](int ldsOff, const unsigned short* g, int grow, int kk) {
        const unsigned short* s0 = g + (size_t)(grow + srcRow0) * 1024 + kk + scolS;
        gl_lds16(s0, lds + ldsOff + wid * 1024 + lane * 8);
        gl_lds16(s0 + 8 * 1024, lds + ldsOff + wid * 1024 + 512 + lane * 8);
    };

    const int fx = fr & 7;
    const int vA0 = wid_m * 4096 + fr * 64 + ((fg ^ fx) << 3);
    const int vA1 = wid_m * 4096 + fr * 64 + (((4 | fg) ^ fx) << 3);
    const int vB0 = wid_n * 4096 + fr * 64 + ((fg ^ fx) << 3);
    const int vB1 = wid_n * 4096 + fr * 64 + (((4 | fg) ^ fx) << 3);

    f32x4 acc[4][4] = {};

    STG(0,            Aact, arow0,       0);
    STG(8192,         Aact, arow0 + 128, 0);
    STG(32768,        Bw, brow0,       0);
    STG(32768 + 8192, Bw, brow0,      64);
    asm volatile("s_waitcnt vmcnt(2)" ::: "memory");
    __builtin_amdgcn_s_barrier();

    for (int t = 0; t < 16; ++t) {
        const int cur = t & 1;
        const int ldA = cur * 16384, ldB = cur * 8192;

        bf16x8 bfr[4][2], af[2][2];
        #pragma unroll
        for (int j = 0; j < 4; ++j) {
            bfr[j][0] = *(const bf16x8*)&ldsB[ldB + vB0 + j * 1024];
            bfr[j][1] = *(const bf16x8*)&ldsB[ldB + vB1 + j * 1024];
        }
        #pragma unroll
        for (int i = 0; i < 2; ++i) {
            af[i][0] = *(const bf16x8*)&ldsA[ldA + vA0 + i * 1024];
            af[i][1] = *(const bf16x8*)&ldsA[ldA + vA1 + i * 1024];
        }
        {
            const int ka = ((t + 1) & 15) * 64;
            STG((cur ^ 1) * 16384,        Aact, arow0,       ka);
            STG((cur ^ 1) * 16384 + 8192, Aact, arow0 + 128, ka);
        }
        __builtin_amdgcn_s_barrier();
        asm volatile("s_waitcnt lgkmcnt(0)" ::: "memory");
        __builtin_amdgcn_s_setprio(1);
        #pragma unroll
        for (int i = 0; i < 2; ++i)
            #pragma unroll
            for (int j = 0; j < 4; ++j) {
                acc[i][j] = __builtin_amdgcn_mfma_f32_16x16x32_bf16(af[i][0], bfr[j][0], acc[i][j], 0, 0, 0);
                acc[i][j] = __builtin_amdgcn_mfma_f32_16x16x32_bf16(af[i][1], bfr[j][1], acc[i][j], 0, 0, 0);
            }
        __builtin_amdgcn_s_setprio(0);
        __builtin_amdgcn_s_barrier();

        bf16x8 af2[2][2];
        #pragma unroll
        for (int i = 0; i < 2; ++i) {
            af2[i][0] = *(const bf16x8*)&ldsA[ldA + vA0 + (2 + i) * 1024];
            af2[i][1] = *(const bf16x8*)&ldsA[ldA + vA1 + (2 + i) * 1024];
        }
        {
            const int kb = ((t + 2) & 15) * 64;
            STG(32768 + ldB, Bw, brow0, kb);
        }
        asm volatile("s_waitcnt vmcnt(2)" ::: "memory");
        __builtin_amdgcn_s_barrier();
        asm volatile("s_waitcnt lgkmcnt(0)" ::: "memory");
        __builtin_amdgcn_s_setprio(1);
        #pragma unroll
        for (int i = 0; i < 2; ++i)
            #pragma unroll
            for (int j = 0; j < 4; ++j) {
                acc[2 + i][j] = __builtin_amdgcn_mfma_f32_16x16x32_bf16(af2[i][0], bfr[j][0], acc[2 + i][j], 0, 0, 0);
                acc[2 + i][j] = __builtin_amdgcn_mfma_f32_16x16x32_bf16(af2[i][1], bfr[j][1], acc[2 + i][j], 0, 0, 0);
            }
        __builtin_amdgcn_s_setprio(0);
        __builtin_amdgcn_s_barrier();
    }
    asm volatile("s_waitcnt vmcnt(0)" ::: "memory");

    const int row00 = bx * 256 + wid_m * 64;
    const int col0 = by * 128 + wid_n * 64;
    #pragma unroll
    for (int i = 0; i < 4; ++i)
        #pragma unroll
        for (int j = 0; j < 4; ++j) {
            int c = col0 + j * 16 + fr;
            float bv = bias[c];
            #pragma unroll
            for (int r = 0; r < 4; ++r) {
                int row = row00 + i * 16 + fg * 4 + r;
                Cf[(size_t)row * 1024 + c] = acc[i][j][r] + bv;
            }
        }
}

// ---------------- Flash attention v5b: balanced per-CU j-sets ----------------
// Same kernel body as v5 (80.5 µs measured); only the block->(head,j) map changes:
// slot k=w>>5, cu c=w&31, s=c>>3, head=c&7; j = k==0?15-s : k==1?8+s : k==2?7-s : s.
// Each CU's 4 resident blocks share one head and their tile counts sum to exactly 68.
__global__ __launch_bounds__(512, 4) void attn_fwd5b(const unsigned short* __restrict__ Qp,
                                                     const unsigned short* __restrict__ Kp,
                                                     const unsigned short* __restrict__ VTg,
                                                     unsigned short* __restrict__ ctx)
{
    __shared__ unsigned short Ks[64][68];
    __shared__ unsigned short Vt[64][68];
    __shared__ unsigned short Ps[8][16][68];

    const int lin = blockIdx.x;
    const int xcd = lin & 7;
    const int w = lin >> 3;                 // 0..127
    const int k = w >> 5;                   // slot 0..3
    const int c = w & 31;                   // CU within XCD (dispatch-order assumption)
    const int s = c >> 3;                   // 0..3
    const int bh = xcd * 8 + (c & 7);       // XCD owns 8 complete heads; CU owns 1
    const int j = (k == 0) ? 15 - s : (k == 1) ? 8 + s : (k == 2) ? 7 - s : s;
    const int b = bh >> 4, h = bh & 15;
    const int tid = threadIdx.x, lane = tid & 63, wid = tid >> 6;
    const int fr = lane & 15, fg = lane >> 4;

    const unsigned short* Qh  = Qp  + (size_t)bh * (S_ * DH_);
    const unsigned short* Kh  = Kp  + (size_t)bh * (S_ * DH_);
    const unsigned short* VTh = VTg + (size_t)bh * (DH_ * S_);

    const int srow = tid >> 3;
    const int scol = (tid & 7) * 8;

    bf16x8 ones;
    #pragma unroll
    for (int i = 0; i < 8; ++i) ones[i] = (__bf16)1.0f;

    const int q0 = j * 128;
    const int ntiles = 2 * (j + 1);
    const int rbase = q0 + wid * 16;
    const int qg = rbase + fr;

    bf16x8 qf[2];
    #pragma unroll
    for (int ks = 0; ks < 2; ++ks)
        qf[ks] = *(const bf16x8*)&Qh[(size_t)qg * 64 + ks * 32 + 8 * fg];

    f32x4 oacc[4] = {};
    float m_run = -3.0e38f, l_run = 0.0f;

    int4 kreg = *(const int4*)&Kh[(size_t)srow * 64 + scol];
    int4 vreg = *(const int4*)&VTh[(size_t)srow * 2048 + scol];

    for (int kt = 0; kt < ntiles; ++kt) {
        const int kv0 = kt * 64;
        __syncthreads();
        *(int4*)&Ks[srow][scol] = kreg;
        *(int4*)&Vt[srow][scol] = vreg;
        if (kt + 1 < ntiles) {
            const int kv1 = kv0 + 64;
            kreg = *(const int4*)&Kh[(size_t)(kv1 + srow) * 64 + scol];
            vreg = *(const int4*)&VTh[(size_t)srow * 2048 + kv1 + scol];
        }
        __syncthreads();

        if (kv0 > rbase + 15) continue;

        f32x4 sacc[4] = {};
        #pragma unroll
        for (int nt = 0; nt < 4; ++nt)
            #pragma unroll
            for (int ks = 0; ks < 2; ++ks) {
                bf16x8 kf = *(const bf16x8*)&Ks[nt * 16 + fr][ks * 32 + 8 * fg];
                sacc[nt] = __builtin_amdgcn_mfma_f32_16x16x32_bf16(kf, qf[ks], sacc[nt], 0, 0, 0);
            }

        if (kv0 + 63 > rbase) {
            const int kbase = kv0 + fg * 4;
            #pragma unroll
            for (int nt = 0; nt < 4; ++nt)
                #pragma unroll
                for (int r = 0; r < 4; ++r)
                    if (kbase + nt * 16 + r > qg) sacc[nt][r] = -3.0e38f;
        }

        float vm = sacc[0][0];
        #pragma unroll
        for (int nt = 0; nt < 4; ++nt)
            #pragma unroll
            for (int r = 0; r < 4; ++r) vm = fmaxf(vm, sacc[nt][r]);
        vm = fmaxf(vm, __shfl_xor(vm, 16));
        vm = fmaxf(vm, __shfl_xor(vm, 32));

        if (!__all(vm - m_run <= 8.0f)) {
            const float mn = fmaxf(m_run, vm);
            const float alpha = exp2f(m_run - mn);
            m_run = mn;
            l_run *= alpha;
            #pragma unroll
            for (int dt = 0; dt < 4; ++dt)
                #pragma unroll
                for (int r = 0; r < 4; ++r) oacc[dt][r] *= alpha;
        }

        #pragma unroll
        for (int nt = 0; nt < 4; ++nt) {
            bf16x4 t;
            t[0] = (__bf16)exp2f(sacc[nt][0] - m_run);
            t[1] = (__bf16)exp2f(sacc[nt][1] - m_run);
            t[2] = (__bf16)exp2f(sacc[nt][2] - m_run);
            t[3] = (__bf16)exp2f(sacc[nt][3] - m_run);
            *(bf16x4*)&Ps[wid][fr][nt * 16 + fg * 4] = t;
        }
        asm volatile("s_waitcnt lgkmcnt(0)" ::: "memory");

        bf16x8 pb[2];
        #pragma unroll
        for (int ks = 0; ks < 2; ++ks)
            pb[ks] = *(const bf16x8*)&Ps[wid][fr][ks * 32 + 8 * fg];

        f32x4 racc = {};
        #pragma unroll
        for (int ks = 0; ks < 2; ++ks)
            racc = __builtin_amdgcn_mfma_f32_16x16x32_bf16(ones, pb[ks], racc, 0, 0, 0);
        #pragma unroll
        for (int dt = 0; dt < 4; ++dt)
            #pragma unroll
            for (int ks = 0; ks < 2; ++ks) {
                bf16x8 vf = *(const bf16x8*)&Vt[dt * 16 + fr][ks * 32 + 8 * fg];
                oacc[dt] = __builtin_amdgcn_mfma_f32_16x16x32_bf16(vf, pb[ks], oacc[dt], 0, 0, 0);
            }
        l_run += racc[0];
    }

    const float linv = 1.0f / l_run;
    unsigned short* cb = &ctx[(size_t)(b * 2048 + qg) * 1024 + h * 64];
    #pragma unroll
    for (int dt = 0; dt < 4; ++dt) {
        unsigned int w0 = f2bf(oacc[dt][0] * linv) | (f2bf(oacc[dt][1] * linv) << 16);
        unsigned int w1 = f2bf(oacc[dt][2] * linv) | (f2bf(oacc[dt][3] * linv) << 16);
        *(uint2*)&cb[dt * 16 + fg * 4] = make_uint2(w0, w1);
    }
}

extern "C" void kernel_launch(void* const* d_in, const int* in_sizes, int n_in,
                              void* d_out, int out_size, void* d_ws, size_t ws_size,
                              hipStream_t stream)
{
    const float* q  = (const float*)d_in[0];
    const float* k  = (const float*)d_in[1];
    const float* v  = (const float*)d_in[2];
    const float* Wq = (const float*)d_in[4];
    const float* bq = (const float*)d_in[5];
    const float* Wk = (const float*)d_in[6];
    const float* bk = (const float*)d_in[7];
    const float* Wv = (const float*)d_in[8];
    const float* bv = (const float*)d_in[9];
    const float* Wo = (const float*)d_in[10];
    const float* bo = (const float*)d_in[11];
    float* out = (float*)d_out;

    unsigned short* Wcat = (unsigned short*)d_ws;          // [Wq;Wk;Wv;Wo] bf16
    unsigned short* actb = Wcat + 4 * 1048576;             // [qb;kb;vb] bf16
    unsigned short* Qp   = actb + 3 * (size_t)NE_;
    unsigned short* Kp   = Qp + NE_;
    unsigned short* VTp  = Kp + NE_;                       // V in [B,H,DH,S]
    unsigned short* Ctx  = VTp + NE_;

    const float SCQ = 0.045084220027780106f;  // log2(e)/sqrt(D)

    dim3 blk(256);
    cvt_all<<<dim3(8192, 7), blk, 0, stream>>>(Wq, Wk, Wv, Wo, q, k, v, Wcat, actb);

    gemm_qkv8<<<dim3(384), dim3(512), 0, stream>>>(actb, Wcat, bq, bk, bv, Qp, Kp, VTp, SCQ);

    attn_fwd5b<<<dim3(1024), dim3(512), 0, stream>>>(Qp, Kp, VTp, Ctx);

    gemm_o2<<<dim3(256), dim3(512), 0, stream>>>(Ctx, Wcat + 3 * 1048576, bo, out);
}

// Round 16
// 201.642 us; speedup vs baseline: 1.0540x; 1.0118x over previous
//
#include <hip/hip_runtime.h>
#include <hip/hip_bf16.h>

#define S_ 2048
#define DH_ 64
#define NE_ 8388608  // 8192*1024 elems per activation tensor

using f32x4  = __attribute__((ext_vector_type(4))) float;
using bf16x8 = __attribute__((ext_vector_type(8))) __bf16;
using bf16x4 = __attribute__((ext_vector_type(4))) __bf16;

__device__ __forceinline__ unsigned int f2bf(float f) {
    union { float f; unsigned int u; } x; x.f = f;
    return (x.u + 0x7FFFu + ((x.u >> 16) & 1u)) >> 16;  // RNE
}

__device__ __forceinline__ float max3f(float a, float b, float c) {
    return fmaxf(fmaxf(a, b), c);   // clang fuses to v_max3_f32
}

// async global->LDS, 16B per lane. LDS dest = wave-uniform base + lane*16.
__device__ __forceinline__ void gl_lds16(const unsigned short* g, unsigned short* l) {
    __builtin_amdgcn_global_load_lds(
        (const __attribute__((address_space(1))) unsigned int*)(const void*)g,
        (__attribute__((address_space(3))) unsigned int*)(void*)l,
        16, 0, 0);
}

// ---------------- fused fp32->bf16 convert: 4 weights + 3 activations ----------------
__global__ __launch_bounds__(256) void cvt_all(const float* __restrict__ w0, const float* __restrict__ w1,
                                               const float* __restrict__ w2, const float* __restrict__ w3,
                                               const float* __restrict__ a0, const float* __restrict__ a1,
                                               const float* __restrict__ a2,
                                               unsigned short* __restrict__ wout,
                                               unsigned short* __restrict__ aout) {
    const int y = blockIdx.y;
    const float* src;
    unsigned short* dst;
    if (y < 4) {
        if (blockIdx.x >= 1024) return;
        src = y == 0 ? w0 : y == 1 ? w1 : y == 2 ? w2 : w3;
        dst = wout + (size_t)y * 1048576;
    } else {
        src = y == 4 ? a0 : y == 5 ? a1 : a2;
        dst = aout + (size_t)(y - 4) * NE_;
    }
    int i = (blockIdx.x * 256 + threadIdx.x) * 4;
    float4 v = *(const float4*)&src[i];
    ushort4 h;
    h.x = f2bf(v.x); h.y = f2bf(v.y); h.z = f2bf(v.z); h.w = f2bf(v.w);
    *(ushort4*)&dst[i] = h;
}

// ---------------- fused QKV projection: 256^2 tile, 8-phase pipelined (r9 measured-best) ----------------
__global__ __launch_bounds__(512, 2) void gemm_qkv8(const unsigned short* __restrict__ actb,
                                                    const unsigned short* __restrict__ Wcat,
                                                    const float* __restrict__ bq,
                                                    const float* __restrict__ bk,
                                                    const float* __restrict__ bvv,
                                                    unsigned short* __restrict__ Qp,
                                                    unsigned short* __restrict__ Kp,
                                                    unsigned short* __restrict__ VTp,
                                                    float scq)
{
    __shared__ unsigned short lds[65536];   // elems: A [0,32768), B [32768,65536)
    unsigned short* ldsA = lds;
    unsigned short* ldsB = lds + 32768;

    // bijective XCD swizzle: nwg=384, q=48, r=0
    const int orig = blockIdx.x;
    const int lid = (orig & 7) * 48 + (orig >> 3);
    const int bx = lid & 31;        // 32 row tiles
    const int by = lid >> 5;        // 12 col tiles
    const int range = by >> 2;      // 0:Q 1:K 2:V
    const unsigned short* Aact = actb + (size_t)range * NE_;

    const int tid = threadIdx.x, lane = tid & 63, wid = tid >> 6;
    const int fr = lane & 15, fg = lane >> 4;
    const int wid_m = wid >> 2, wid_n = wid & 3;

    // staging maps (per-lane): lds linear dest, slot-XOR pre-swizzled global source
    const int srcRow0 = wid * 16 + (lane >> 3);                       // u=0; u=1: +8
    const int scolS = ((lane & 7) ^ ((lane >> 3) & 7)) << 3;          // elems

    auto STG = [&](int ldsRegion, const unsigned short* g, int grow, int kk) {
        const unsigned short* s0 = g + (size_t)(grow + srcRow0) * 1024 + kk + scolS;
        gl_lds16(s0, lds + ldsRegion + wid * 1024 + lane * 8);
        gl_lds16(s0 + 8 * 1024, lds + ldsRegion + wid * 1024 + 512 + lane * 8);
    };

    // ds_read bases (elems), slot-XOR swizzle: slot (ks*4+fg) ^ (fr&7)
    const int fx = fr & 7;
    const int vA0 = wid_m * 8192 + fr * 64 + ((fg ^ fx) << 3);
    const int vA1 = wid_m * 8192 + fr * 64 + (((4 | fg) ^ fx) << 3);
    const int vBr = (wid_n & 1) * 4096 + (wid_n >> 1) * 8192 + fr * 64;
    const int vB0 = vBr + ((fg ^ fx) << 3);
    const int vB1 = vBr + (((4 | fg) ^ fx) << 3);

    f32x4 acc[8][4] = {};
    bf16x8 bfr[4][2];

    // prologue: A-buf0<-T0 (h0,h1), B-buf0<-T0, B-buf1<-T1; retire first 8, keep 4
    STG(0,          Aact, bx * 256,       0);
    STG(8192,       Aact, bx * 256 + 128, 0);
    STG(32768,      Wcat, by * 256,       0);
    STG(32768+8192, Wcat, by * 256 + 128, 0);
    STG(32768+16384,       Wcat, by * 256,       64);
    STG(32768+16384+8192,  Wcat, by * 256 + 128,  64);
    asm volatile("s_waitcnt vmcnt(4)" ::: "memory");
    __builtin_amdgcn_s_barrier();

#define KTILE(BUF, ABUF, TA, BBUF, TB)                                              \
  {                                                                                 \
    _Pragma("unroll")                                                               \
    for (int q = 0; q < 4; ++q) {                                                   \
      if (q == 0) {                                                                 \
        _Pragma("unroll")                                                           \
        for (int j = 0; j < 4; ++j) {                                               \
          bfr[j][0] = *(const bf16x8*)&ldsB[(BUF)*16384 + vB0 + j*1024];            \
          bfr[j][1] = *(const bf16x8*)&ldsB[(BUF)*16384 + vB1 + j*1024];            \
        }                                                                           \
      }                                                                             \
      bf16x8 af[2][2];                                                              \
      _Pragma("unroll")                                                             \
      for (int i2 = 0; i2 < 2; ++i2) {                                              \
        af[i2][0] = *(const bf16x8*)&ldsA[(BUF)*16384 + vA0 + (q*2+i2)*1024];       \
        af[i2][1] = *(const bf16x8*)&ldsA[(BUF)*16384 + vA1 + (q*2+i2)*1024];       \
      }                                                                             \
      if (q == 0) STG((ABUF)*16384,        Aact, bx*256,       ((TA)&15)*64);       \
      if (q == 1) STG((ABUF)*16384 + 8192, Aact, bx*256 + 128, ((TA)&15)*64);       \
      if (q == 2) STG(32768 + (BBUF)*16384,        Wcat, by*256,       ((TB)&15)*64); \
      if (q == 3) { STG(32768 + (BBUF)*16384 + 8192, Wcat, by*256 + 128, ((TB)&15)*64); \
                    asm volatile("s_waitcnt vmcnt(4)" ::: "memory"); }              \
      __builtin_amdgcn_s_barrier();                                                 \
      asm volatile("s_waitcnt lgkmcnt(0)" ::: "memory");                            \
      __builtin_amdgcn_s_setprio(1);                                                \
      _Pragma("unroll")                                                             \
      for (int i2 = 0; i2 < 2; ++i2)                                                \
        _Pragma("unroll")                                                           \
        for (int j = 0; j < 4; ++j) {                                               \
          acc[q*2+i2][j] = __builtin_amdgcn_mfma_f32_16x16x32_bf16(af[i2][0], bfr[j][0], acc[q*2+i2][j], 0, 0, 0); \
          acc[q*2+i2][j] = __builtin_amdgcn_mfma_f32_16x16x32_bf16(af[i2][1], bfr[j][1], acc[q*2+i2][j], 0, 0, 0); \
        }                                                                           \
      __builtin_amdgcn_s_setprio(0);                                                \
      __builtin_amdgcn_s_barrier();                                                 \
    }                                                                               \
  }

    for (int it = 0; it < 8; ++it) {
        const int t0 = 2 * it;
        KTILE(0, 1, t0 + 1, 0, t0 + 2);   // phases 1-4: read buf0; stage A-buf1<-T1, B-buf0<-T2
        KTILE(1, 0, t0 + 2, 1, t0 + 3);   // phases 5-8: read buf1; stage A-buf0<-T2, B-buf1<-T3
    }
#undef KTILE

    asm volatile("s_waitcnt vmcnt(0)" ::: "memory");  // drain dummy prefetches before exit

    // epilogue: wave owns rows [wid_m*128,+128) x cols [wid_n*64,+64) of the 256^2 tile
    const float* bp = range == 0 ? bq : range == 1 ? bk : bvv;
    const float os = range == 0 ? scq : 1.0f;
    unsigned short* OP = range == 0 ? Qp : Kp;
    const int row00 = bx * 256 + wid_m * 128;
    const int col0r = (by & 3) * 256 + wid_n * 64;   // within range [0,1024)

    #pragma unroll
    for (int i = 0; i < 8; ++i) {
        #pragma unroll
        for (int j = 0; j < 4; ++j) {
            int colr = col0r + j * 16 + fr;
            float bias = bp[colr];
            int h = colr >> 6, dh = colr & 63;
            if (range == 2) {
                int row = row00 + i * 16 + fg * 4;
                int b = row >> 11, s = row & 2047;
                unsigned int w0 = f2bf(acc[i][j][0] + bias) | (f2bf(acc[i][j][1] + bias) << 16);
                unsigned int w1 = f2bf(acc[i][j][2] + bias) | (f2bf(acc[i][j][3] + bias) << 16);
                *(uint2*)&VTp[((size_t)((b << 4) + h) * 64 + dh) * 2048 + s] = make_uint2(w0, w1);
            } else {
                #pragma unroll
                for (int r = 0; r < 4; ++r) {
                    int row = row00 + i * 16 + fg * 4 + r;
                    int b = row >> 11, s = row & 2047;
                    OP[((((b << 4) + h) * 2048 + s) << 6) + dh] =
                        (unsigned short)f2bf((acc[i][j][r] + bias) * os);
                }
            }
        }
    }
}

// ---------------- output projection: 256x128-tile 2-phase (r14 winner for gemm_o) ----------------
__global__ __launch_bounds__(512, 2) void gemm_o2(const unsigned short* __restrict__ Aact,
                                                  const unsigned short* __restrict__ Bw,
                                                  const float* __restrict__ bias,
                                                  float* __restrict__ Cf)
{
    __shared__ unsigned short lds[49152];   // elems: A [0,32768), B [32768,49152)
    unsigned short* ldsA = lds;
    unsigned short* ldsB = lds + 32768;

    const int q8 = gridDim.x >> 3;
    const int lid = (blockIdx.x & 7) * q8 + (blockIdx.x >> 3);
    const int bx = lid & 31;
    const int by = lid >> 5;

    const int arow0 = bx * 256;
    const int brow0 = by * 128;

    const int tid = threadIdx.x, lane = tid & 63, wid = tid >> 6;
    const int fr = lane & 15, fg = lane >> 4;
    const int wid_m = wid >> 1, wid_n = wid & 1;

    const int srcRow0 = wid * 16 + (lane >> 3);
    const int scolS = ((lane & 7) ^ ((lane >> 3) & 7)) << 3;

    auto STG = [&](int ldsOff, const unsigned short* g, int grow, int kk) {
        const unsigned short* s0 = g + (size_t)(grow + srcRow0) * 1024 + kk + scolS;
        gl_lds16(s0, lds + ldsOff + wid * 1024 + lane * 8);
        gl_lds16(s0 + 8 * 1024, lds + ldsOff + wid * 1024 + 512 + lane * 8);
    };

    const int fx = fr & 7;
    const int vA0 = wid_m * 4096 + fr * 64 + ((fg ^ fx) << 3);
    const int vA1 = wid_m * 4096 + fr * 64 + (((4 | fg) ^ fx) << 3);
    const int vB0 = wid_n * 4096 + fr * 64 + ((fg ^ fx) << 3);
    const int vB1 = wid_n * 4096 + fr * 64 + (((4 | fg) ^ fx) << 3);

    f32x4 acc[4][4] = {};

    STG(0,            Aact, arow0,       0);
    STG(8192,         Aact, arow0 + 128, 0);
    STG(32768,        Bw, brow0,       0);
    STG(32768 + 8192, Bw, brow0,      64);
    asm volatile("s_waitcnt vmcnt(2)" ::: "memory");
    __builtin_amdgcn_s_barrier();

    for (int t = 0; t < 16; ++t) {
        const int cur = t & 1;
        const int ldA = cur * 16384, ldB = cur * 8192;

        bf16x8 bfr[4][2], af[2][2];
        #pragma unroll
        for (int j = 0; j < 4; ++j) {
            bfr[j][0] = *(const bf16x8*)&ldsB[ldB + vB0 + j * 1024];
            bfr[j][1] = *(const bf16x8*)&ldsB[ldB + vB1 + j * 1024];
        }
        #pragma unroll
        for (int i = 0; i < 2; ++i) {
            af[i][0] = *(const bf16x8*)&ldsA[ldA + vA0 + i * 1024];
            af[i][1] = *(const bf16x8*)&ldsA[ldA + vA1 + i * 1024];
        }
        {
            const int ka = ((t + 1) & 15) * 64;
            STG((cur ^ 1) * 16384,        Aact, arow0,       ka);
            STG((cur ^ 1) * 16384 + 8192, Aact, arow0 + 128, ka);
        }
        __builtin_amdgcn_s_barrier();
        asm volatile("s_waitcnt lgkmcnt(0)" ::: "memory");
        __builtin_amdgcn_s_setprio(1);
        #pragma unroll
        for (int i = 0; i < 2; ++i)
            #pragma unroll
            for (int j = 0; j < 4; ++j) {
                acc[i][j] = __builtin_amdgcn_mfma_f32_16x16x32_bf16(af[i][0], bfr[j][0], acc[i][j], 0, 0, 0);
                acc[i][j] = __builtin_amdgcn_mfma_f32_16x16x32_bf16(af[i][1], bfr[j][1], acc[i][j], 0, 0, 0);
            }
        __builtin_amdgcn_s_setprio(0);
        __builtin_amdgcn_s_barrier();

        bf16x8 af2[2][2];
        #pragma unroll
        for (int i = 0; i < 2; ++i) {
            af2[i][0] = *(const bf16x8*)&ldsA[ldA + vA0 + (2 + i) * 1024];
            af2[i][1] = *(const bf16x8*)&ldsA[ldA + vA1 + (2 + i) * 1024];
        }
        {
            const int kb = ((t + 2) & 15) * 64;
            STG(32768 + ldB, Bw, brow0, kb);
        }
        asm volatile("s_waitcnt vmcnt(2)" ::: "memory");
        __builtin_amdgcn_s_barrier();
        asm volatile("s_waitcnt lgkmcnt(0)" ::: "memory");
        __builtin_amdgcn_s_setprio(1);
        #pragma unroll
        for (int i = 0; i < 2; ++i)
            #pragma unroll
            for (int j = 0; j < 4; ++j) {
                acc[2 + i][j] = __builtin_amdgcn_mfma_f32_16x16x32_bf16(af2[i][0], bfr[j][0], acc[2 + i][j], 0, 0, 0);
                acc[2 + i][j] = __builtin_amdgcn_mfma_f32_16x16x32_bf16(af2[i][1], bfr[j][1], acc[2 + i][j], 0, 0, 0);
            }
        __builtin_amdgcn_s_setprio(0);
        __builtin_amdgcn_s_barrier();
    }
    asm volatile("s_waitcnt vmcnt(0)" ::: "memory");

    const int row00 = bx * 256 + wid_m * 64;
    const int col0 = by * 128 + wid_n * 64;
    #pragma unroll
    for (int i = 0; i < 4; ++i)
        #pragma unroll
        for (int j = 0; j < 4; ++j) {
            int c = col0 + j * 16 + fr;
            float bv = bias[c];
            #pragma unroll
            for (int r = 0; r < 4; ++r) {
                int row = row00 + i * 16 + fg * 4 + r;
                Cf[(size_t)row * 1024 + c] = acc[i][j][r] + bv;
            }
        }
}

// ---------------- Flash attention v5 (r13 measured-best mapping) + max3 tree ----------------
__global__ __launch_bounds__(512, 4) void attn_fwd5(const unsigned short* __restrict__ Qp,
                                                    const unsigned short* __restrict__ Kp,
                                                    const unsigned short* __restrict__ VTg,
                                                    unsigned short* __restrict__ ctx)
{
    __shared__ unsigned short Ks[64][68];
    __shared__ unsigned short Vt[64][68];
    __shared__ unsigned short Ps[8][16][68];

    const int lin = blockIdx.x;
    const int xcd = lin & 7;
    const int w = lin >> 3;
    const int bh = xcd * 8 + (w & 7);     // XCD owns 8 complete heads
    const int j = 15 - (w >> 3);          // heavy blocks first
    const int b = bh >> 4, h = bh & 15;
    const int tid = threadIdx.x, lane = tid & 63, wid = tid >> 6;
    const int fr = lane & 15, fg = lane >> 4;

    const unsigned short* Qh  = Qp  + (size_t)bh * (S_ * DH_);
    const unsigned short* Kh  = Kp  + (size_t)bh * (S_ * DH_);
    const unsigned short* VTh = VTg + (size_t)bh * (DH_ * S_);

    const int srow = tid >> 3;
    const int scol = (tid & 7) * 8;

    bf16x8 ones;
    #pragma unroll
    for (int i = 0; i < 8; ++i) ones[i] = (__bf16)1.0f;

    const int q0 = j * 128;
    const int ntiles = 2 * (j + 1);
    const int rbase = q0 + wid * 16;
    const int qg = rbase + fr;

    bf16x8 qf[2];
    #pragma unroll
    for (int ks = 0; ks < 2; ++ks)
        qf[ks] = *(const bf16x8*)&Qh[(size_t)qg * 64 + ks * 32 + 8 * fg];

    f32x4 oacc[4] = {};
    float m_run = -3.0e38f, l_run = 0.0f;

    int4 kreg = *(const int4*)&Kh[(size_t)srow * 64 + scol];
    int4 vreg = *(const int4*)&VTh[(size_t)srow * 2048 + scol];

    for (int kt = 0; kt < ntiles; ++kt) {
        const int kv0 = kt * 64;
        __syncthreads();
        *(int4*)&Ks[srow][scol] = kreg;
        *(int4*)&Vt[srow][scol] = vreg;
        if (kt + 1 < ntiles) {
            const int kv1 = kv0 + 64;
            kreg = *(const int4*)&Kh[(size_t)(kv1 + srow) * 64 + scol];
            vreg = *(const int4*)&VTh[(size_t)srow * 2048 + kv1 + scol];
        }
        __syncthreads();

        if (kv0 > rbase + 15) continue;

        f32x4 sacc[4] = {};
        #pragma unroll
        for (int nt = 0; nt < 4; ++nt)
            #pragma unroll
            for (int ks = 0; ks < 2; ++ks) {
                bf16x8 kf = *(const bf16x8*)&Ks[nt * 16 + fr][ks * 32 + 8 * fg];
                sacc[nt] = __builtin_amdgcn_mfma_f32_16x16x32_bf16(kf, qf[ks], sacc[nt], 0, 0, 0);
            }

        if (kv0 + 63 > rbase) {
            const int kbase = kv0 + fg * 4;
            #pragma unroll
            for (int nt = 0; nt < 4; ++nt)
                #pragma unroll
                for (int r = 0; r < 4; ++r)
                    if (kbase + nt * 16 + r > qg) sacc[nt][r] = -3.0e38f;
        }

        // row max over 16 in-lane values: max3 tree (7 ops) + 2 cross-fg shuffles
        float ta = max3f(sacc[0][0], sacc[0][1], sacc[0][2]);
        float tb = max3f(sacc[0][3], sacc[1][0], sacc[1][1]);
        float tc = max3f(sacc[1][2], sacc[1][3], sacc[2][0]);
        float td = max3f(sacc[2][1], sacc[2][2], sacc[2][3]);
        float te = max3f(sacc[3][0], sacc[3][1], sacc[3][2]);
        float vm = fmaxf(max3f(ta, tb, sacc[3][3]), max3f(tc, td, te));
        vm = fmaxf(vm, __shfl_xor(vm, 16));
        vm = fmaxf(vm, __shfl_xor(vm, 32));

        if (!__all(vm - m_run <= 8.0f)) {
            const float mn = fmaxf(m_run, vm);
            const float alpha = exp2f(m_run - mn);
            m_run = mn;
            l_run *= alpha;
            #pragma unroll
            for (int dt = 0; dt < 4; ++dt)
                #pragma unroll
                for (int r = 0; r < 4; ++r) oacc[dt][r] *= alpha;
        }

        #pragma unroll
        for (int nt = 0; nt < 4; ++nt) {
            bf16x4 t;
            t[0] = (__bf16)exp2f(sacc[nt][0] - m_run);
            t[1] = (__bf16)exp2f(sacc[nt][1] - m_run);
            t[2] = (__bf16)exp2f(sacc[nt][2] - m_run);
            t[3] = (__bf16)exp2f(sacc[nt][3] - m_run);
            *(bf16x4*)&Ps[wid][fr][nt * 16 + fg * 4] = t;
        }
        asm volatile("s_waitcnt lgkmcnt(0)" ::: "memory");

        bf16x8 pb[2];
        #pragma unroll
        for (int ks = 0; ks < 2; ++ks)
            pb[ks] = *(const bf16x8*)&Ps[wid][fr][ks * 32 + 8 * fg];

        f32x4 racc = {};
        #pragma unroll
        for (int ks = 0; ks < 2; ++ks)
            racc = __builtin_amdgcn_mfma_f32_16x16x32_bf16(ones, pb[ks], racc, 0, 0, 0);
        #pragma unroll
        for (int dt = 0; dt < 4; ++dt)
            #pragma unroll
            for (int ks = 0; ks < 2; ++ks) {
                bf16x8 vf = *(const bf16x8*)&Vt[dt * 16 + fr][ks * 32 + 8 * fg];
                oacc[dt] = __builtin_amdgcn_mfma_f32_16x16x32_bf16(vf, pb[ks], oacc[dt], 0, 0, 0);
            }
        l_run += racc[0];
    }

    const float linv = 1.0f / l_run;
    unsigned short* cb = &ctx[(size_t)(b * 2048 + qg) * 1024 + h * 64];
    #pragma unroll
    for (int dt = 0; dt < 4; ++dt) {
        unsigned int w0 = f2bf(oacc[dt][0] * linv) | (f2bf(oacc[dt][1] * linv) << 16);
        unsigned int w1 = f2bf(oacc[dt][2] * linv) | (f2bf(oacc[dt][3] * linv) << 16);
        *(uint2*)&cb[dt * 16 + fg * 4] = make_uint2(w0, w1);
    }
}

extern "C" void kernel_launch(void* const* d_in, const int* in_sizes, int n_in,
                              void* d_out, int out_size, void* d_ws, size_t ws_size,
                              hipStream_t stream)
{
    const float* q  = (const float*)d_in[0];
    const float* k  = (const float*)d_in[1];
    const float* v  = (const float*)d_in[2];
    const float* Wq = (const float*)d_in[4];
    const float* bq = (const float*)d_in[5];
    const float* Wk = (const float*)d_in[6];
    const float* bk = (const float*)d_in[7];
    const float* Wv = (const float*)d_in[8];
    const float* bv = (const float*)d_in[9];
    const float* Wo = (const float*)d_in[10];
    const float* bo = (const float*)d_in[11];
    float* out = (float*)d_out;

    unsigned short* Wcat = (unsigned short*)d_ws;          // [Wq;Wk;Wv;Wo] bf16
    unsigned short* actb = Wcat + 4 * 1048576;             // [qb;kb;vb] bf16
    unsigned short* Qp   = actb + 3 * (size_t)NE_;
    unsigned short* Kp   = Qp + NE_;
    unsigned short* VTp  = Kp + NE_;                       // V in [B,H,DH,S]
    unsigned short* Ctx  = VTp + NE_;

    const float SCQ = 0.045084220027780106f;  // log2(e)/sqrt(D)

    dim3 blk(256);
    cvt_all<<<dim3(8192, 7), blk, 0, stream>>>(Wq, Wk, Wv, Wo, q, k, v, Wcat, actb);

    gemm_qkv8<<<dim3(384), dim3(512), 0, stream>>>(actb, Wcat, bq, bk, bv, Qp, Kp, VTp, SCQ);

    attn_fwd5<<<dim3(1024), dim3(512), 0, stream>>>(Qp, Kp, VTp, Ctx);

    gemm_o2<<<dim3(256), dim3(512), 0, stream>>>(Ctx, Wcat + 3 * 1048576, bo, out);
}

// Round 17
// 196.529 us; speedup vs baseline: 1.0814x; 1.0260x over previous
//
#include <hip/hip_runtime.h>
#include <hip/hip_bf16.h>

#define S_ 2048
#define DH_ 64
#define NE_ 8388608  // 8192*1024 elems per activation tensor

using f32x4  = __attribute__((ext_vector_type(4))) float;
using bf16x8 = __attribute__((ext_vector_type(8))) __bf16;
using bf16x4 = __attribute__((ext_vector_type(4))) __bf16;

__device__ __forceinline__ unsigned int f2bf(float f) {
    union { float f; unsigned int u; } x; x.f = f;
    return (x.u + 0x7FFFu + ((x.u >> 16) & 1u)) >> 16;  // RNE
}

__device__ __forceinline__ float max3f(float a, float b, float c) {
    return fmaxf(fmaxf(a, b), c);   // clang fuses to v_max3_f32
}

// async global->LDS, 16B per lane. LDS dest = wave-uniform base + lane*16.
__device__ __forceinline__ void gl_lds16(const unsigned short* g, unsigned short* l) {
    __builtin_amdgcn_global_load_lds(
        (const __attribute__((address_space(1))) unsigned int*)(const void*)g,
        (__attribute__((address_space(3))) unsigned int*)(void*)l,
        16, 0, 0);
}

// ---------------- fused fp32->bf16 convert: 4 weights + 3 activations ----------------
__global__ __launch_bounds__(256) void cvt_all(const float* __restrict__ w0, const float* __restrict__ w1,
                                               const float* __restrict__ w2, const float* __restrict__ w3,
                                               const float* __restrict__ a0, const float* __restrict__ a1,
                                               const float* __restrict__ a2,
                                               unsigned short* __restrict__ wout,
                                               unsigned short* __restrict__ aout) {
    const int y = blockIdx.y;
    const float* src;
    unsigned short* dst;
    if (y < 4) {
        if (blockIdx.x >= 1024) return;
        src = y == 0 ? w0 : y == 1 ? w1 : y == 2 ? w2 : w3;
        dst = wout + (size_t)y * 1048576;
    } else {
        src = y == 4 ? a0 : y == 5 ? a1 : a2;
        dst = aout + (size_t)(y - 4) * NE_;
    }
    int i = (blockIdx.x * 256 + threadIdx.x) * 4;
    float4 v = *(const float4*)&src[i];
    ushort4 h;
    h.x = f2bf(v.x); h.y = f2bf(v.y); h.z = f2bf(v.z); h.w = f2bf(v.w);
    *(ushort4*)&dst[i] = h;
}

// ---------------- fused QKV projection: 256^2 tile, 8-phase pipelined ----------------
// r17 change: tile map bx=lid/12, by=lid%12 -> each XCD owns 4 contiguous row-panels
// x all col-panels: per-XCD A working set ~4MB (L2-fits) instead of 48MB streaming.
__global__ __launch_bounds__(512, 2) void gemm_qkv8(const unsigned short* __restrict__ actb,
                                                    const unsigned short* __restrict__ Wcat,
                                                    const float* __restrict__ bq,
                                                    const float* __restrict__ bk,
                                                    const float* __restrict__ bvv,
                                                    unsigned short* __restrict__ Qp,
                                                    unsigned short* __restrict__ Kp,
                                                    unsigned short* __restrict__ VTp,
                                                    float scq)
{
    __shared__ unsigned short lds[65536];   // elems: A [0,32768), B [32768,65536)
    unsigned short* ldsA = lds;
    unsigned short* ldsB = lds + 32768;

    // bijective XCD swizzle: nwg=384, q=48, r=0
    const int orig = blockIdx.x;
    const int lid = (orig & 7) * 48 + (orig >> 3);
    const int bx = lid / 12;        // 32 row tiles (4 contiguous per XCD)
    const int by = lid % 12;        // 12 col tiles
    const int range = by >> 2;      // 0:Q 1:K 2:V
    const unsigned short* Aact = actb + (size_t)range * NE_;

    const int tid = threadIdx.x, lane = tid & 63, wid = tid >> 6;
    const int fr = lane & 15, fg = lane >> 4;
    const int wid_m = wid >> 2, wid_n = wid & 3;

    // staging maps (per-lane): lds linear dest, slot-XOR pre-swizzled global source
    const int srcRow0 = wid * 16 + (lane >> 3);                       // u=0; u=1: +8
    const int scolS = ((lane & 7) ^ ((lane >> 3) & 7)) << 3;          // elems

    auto STG = [&](int ldsRegion, const unsigned short* g, int grow, int kk) {
        const unsigned short* s0 = g + (size_t)(grow + srcRow0) * 1024 + kk + scolS;
        gl_lds16(s0, lds + ldsRegion + wid * 1024 + lane * 8);
        gl_lds16(s0 + 8 * 1024, lds + ldsRegion + wid * 1024 + 512 + lane * 8);
    };

    // ds_read bases (elems), slot-XOR swizzle: slot (ks*4+fg) ^ (fr&7)
    const int fx = fr & 7;
    const int vA0 = wid_m * 8192 + fr * 64 + ((fg ^ fx) << 3);
    const int vA1 = wid_m * 8192 + fr * 64 + (((4 | fg) ^ fx) << 3);
    const int vBr = (wid_n & 1) * 4096 + (wid_n >> 1) * 8192 + fr * 64;
    const int vB0 = vBr + ((fg ^ fx) << 3);
    const int vB1 = vBr + (((4 | fg) ^ fx) << 3);

    f32x4 acc[8][4] = {};
    bf16x8 bfr[4][2];

    // prologue: A-buf0<-T0 (h0,h1), B-buf0<-T0, B-buf1<-T1; retire first 8, keep 4
    STG(0,          Aact, bx * 256,       0);
    STG(8192,       Aact, bx * 256 + 128, 0);
    STG(32768,      Wcat, by * 256,       0);
    STG(32768+8192, Wcat, by * 256 + 128, 0);
    STG(32768+16384,       Wcat, by * 256,       64);
    STG(32768+16384+8192,  Wcat, by * 256 + 128,  64);
    asm volatile("s_waitcnt vmcnt(4)" ::: "memory");
    __builtin_amdgcn_s_barrier();

#define KTILE(BUF, ABUF, TA, BBUF, TB)                                              \
  {                                                                                 \
    _Pragma("unroll")                                                               \
    for (int q = 0; q < 4; ++q) {                                                   \
      if (q == 0) {                                                                 \
        _Pragma("unroll")                                                           \
        for (int j = 0; j < 4; ++j) {                                               \
          bfr[j][0] = *(const bf16x8*)&ldsB[(BUF)*16384 + vB0 + j*1024];            \
          bfr[j][1] = *(const bf16x8*)&ldsB[(BUF)*16384 + vB1 + j*1024];            \
        }                                                                           \
      }                                                                             \
      bf16x8 af[2][2];                                                              \
      _Pragma("unroll")                                                             \
      for (int i2 = 0; i2 < 2; ++i2) {                                              \
        af[i2][0] = *(const bf16x8*)&ldsA[(BUF)*16384 + vA0 + (q*2+i2)*1024];       \
        af[i2][1] = *(const bf16x8*)&ldsA[(BUF)*16384 + vA1 + (q*2+i2)*1024];       \
      }                                                                             \
      if (q == 0) STG((ABUF)*16384,        Aact, bx*256,       ((TA)&15)*64);       \
      if (q == 1) STG((ABUF)*16384 + 8192, Aact, bx*256 + 128, ((TA)&15)*64);       \
      if (q == 2) STG(32768 + (BBUF)*16384,        Wcat, by*256,       ((TB)&15)*64); \
      if (q == 3) { STG(32768 + (BBUF)*16384 + 8192, Wcat, by*256 + 128, ((TB)&15)*64); \
                    asm volatile("s_waitcnt vmcnt(4)" ::: "memory"); }              \
      __builtin_amdgcn_s_barrier();                                                 \
      asm volatile("s_waitcnt lgkmcnt(0)" ::: "memory");                            \
      __builtin_amdgcn_s_setprio(1);                                                \
      _Pragma("unroll")                                                             \
      for (int i2 = 0; i2 < 2; ++i2)                                                \
        _Pragma("unroll")                                                           \
        for (int j = 0; j < 4; ++j) {                                               \
          acc[q*2+i2][j] = __builtin_amdgcn_mfma_f32_16x16x32_bf16(af[i2][0], bfr[j][0], acc[q*2+i2][j], 0, 0, 0); \
          acc[q*2+i2][j] = __builtin_amdgcn_mfma_f32_16x16x32_bf16(af[i2][1], bfr[j][1], acc[q*2+i2][j], 0, 0, 0); \
        }                                                                           \
      __builtin_amdgcn_s_setprio(0);                                                \
      __builtin_amdgcn_s_barrier();                                                 \
    }                                                                               \
  }

    for (int it = 0; it < 8; ++it) {
        const int t0 = 2 * it;
        KTILE(0, 1, t0 + 1, 0, t0 + 2);   // phases 1-4: read buf0; stage A-buf1<-T1, B-buf0<-T2
        KTILE(1, 0, t0 + 2, 1, t0 + 3);   // phases 5-8: read buf1; stage A-buf0<-T2, B-buf1<-T3
    }
#undef KTILE

    asm volatile("s_waitcnt vmcnt(0)" ::: "memory");  // drain dummy prefetches before exit

    // epilogue: wave owns rows [wid_m*128,+128) x cols [wid_n*64,+64) of the 256^2 tile
    const float* bp = range == 0 ? bq : range == 1 ? bk : bvv;
    const float os = range == 0 ? scq : 1.0f;
    unsigned short* OP = range == 0 ? Qp : Kp;
    const int row00 = bx * 256 + wid_m * 128;
    const int col0r = (by & 3) * 256 + wid_n * 64;   // within range [0,1024)

    #pragma unroll
    for (int i = 0; i < 8; ++i) {
        #pragma unroll
        for (int j = 0; j < 4; ++j) {
            int colr = col0r + j * 16 + fr;
            float bias = bp[colr];
            int h = colr >> 6, dh = colr & 63;
            if (range == 2) {
                int row = row00 + i * 16 + fg * 4;
                int b = row >> 11, s = row & 2047;
                unsigned int w0 = f2bf(acc[i][j][0] + bias) | (f2bf(acc[i][j][1] + bias) << 16);
                unsigned int w1 = f2bf(acc[i][j][2] + bias) | (f2bf(acc[i][j][3] + bias) << 16);
                *(uint2*)&VTp[((size_t)((b << 4) + h) * 64 + dh) * 2048 + s] = make_uint2(w0, w1);
            } else {
                #pragma unroll
                for (int r = 0; r < 4; ++r) {
                    int row = row00 + i * 16 + fg * 4 + r;
                    int b = row >> 11, s = row & 2047;
                    OP[((((b << 4) + h) * 2048 + s) << 6) + dh] =
                        (unsigned short)f2bf((acc[i][j][r] + bias) * os);
                }
            }
        }
    }
}

// ---------------- output projection: 256x128-tile 2-phase (r14 winner for gemm_o) ----------------
__global__ __launch_bounds__(512, 2) void gemm_o2(const unsigned short* __restrict__ Aact,
                                                  const unsigned short* __restrict__ Bw,
                                                  const float* __restrict__ bias,
                                                  float* __restrict__ Cf)
{
    __shared__ unsigned short lds[49152];   // elems: A [0,32768), B [32768,49152)
    unsigned short* ldsA = lds;
    unsigned short* ldsB = lds + 32768;

    const int q8 = gridDim.x >> 3;
    const int lid = (blockIdx.x & 7) * q8 + (blockIdx.x >> 3);
    const int bx = lid & 31;
    const int by = lid >> 5;

    const int arow0 = bx * 256;
    const int brow0 = by * 128;

    const int tid = threadIdx.x, lane = tid & 63, wid = tid >> 6;
    const int fr = lane & 15, fg = lane >> 4;
    const int wid_m = wid >> 1, wid_n = wid & 1;

    const int srcRow0 = wid * 16 + (lane >> 3);
    const int scolS = ((lane & 7) ^ ((lane >> 3) & 7)) << 3;

    auto STG = [&](int ldsOff, const unsigned short* g, int grow, int kk) {
        const unsigned short* s0 = g + (size_t)(grow + srcRow0) * 1024 + kk + scolS;
        gl_lds16(s0, lds + ldsOff + wid * 1024 + lane * 8);
        gl_lds16(s0 + 8 * 1024, lds + ldsOff + wid * 1024 + 512 + lane * 8);
    };

    const int fx = fr & 7;
    const int vA0 = wid_m * 4096 + fr * 64 + ((fg ^ fx) << 3);
    const int vA1 = wid_m * 4096 + fr * 64 + (((4 | fg) ^ fx) << 3);
    const int vB0 = wid_n * 4096 + fr * 64 + ((fg ^ fx) << 3);
    const int vB1 = wid_n * 4096 + fr * 64 + (((4 | fg) ^ fx) << 3);

    f32x4 acc[4][4] = {};

    STG(0,            Aact, arow0,       0);
    STG(8192,         Aact, arow0 + 128, 0);
    STG(32768,        Bw, brow0,       0);
    STG(32768 + 8192, Bw, brow0,      64);
    asm volatile("s_waitcnt vmcnt(2)" ::: "memory");
    __builtin_amdgcn_s_barrier();

    for (int t = 0; t < 16; ++t) {
        const int cur = t & 1;
        const int ldA = cur * 16384, ldB = cur * 8192;

        bf16x8 bfr[4][2], af[2][2];
        #pragma unroll
        for (int j = 0; j < 4; ++j) {
            bfr[j][0] = *(const bf16x8*)&ldsB[ldB + vB0 + j * 1024];
            bfr[j][1] = *(const bf16x8*)&ldsB[ldB + vB1 + j * 1024];
        }
        #pragma unroll
        for (int i = 0; i < 2; ++i) {
            af[i][0] = *(const bf16x8*)&ldsA[ldA + vA0 + i * 1024];
            af[i][1] = *(const bf16x8*)&ldsA[ldA + vA1 + i * 1024];
        }
        {
            const int ka = ((t + 1) & 15) * 64;
            STG((cur ^ 1) * 16384,        Aact, arow0,       ka);
            STG((cur ^ 1) * 16384 + 8192, Aact, arow0 + 128, ka);
        }
        __builtin_amdgcn_s_barrier();
        asm volatile("s_waitcnt lgkmcnt(0)" ::: "memory");
        __builtin_amdgcn_s_setprio(1);
        #pragma unroll
        for (int i = 0; i < 2; ++i)
            #pragma unroll
            for (int j = 0; j < 4; ++j) {
                acc[i][j] = __builtin_amdgcn_mfma_f32_16x16x32_bf16(af[i][0], bfr[j][0], acc[i][j], 0, 0, 0);
                acc[i][j] = __builtin_amdgcn_mfma_f32_16x16x32_bf16(af[i][1], bfr[j][1], acc[i][j], 0, 0, 0);
            }
        __builtin_amdgcn_s_setprio(0);
        __builtin_amdgcn_s_barrier();

        bf16x8 af2[2][2];
        #pragma unroll
        for (int i = 0; i < 2; ++i) {
            af2[i][0] = *(const bf16x8*)&ldsA[ldA + vA0 + (2 + i) * 1024];
            af2[i][1] = *(const bf16x8*)&ldsA[ldA + vA1 + (2 + i) * 1024];
        }
        {
            const int kb = ((t + 2) & 15) * 64;
            STG(32768 + ldB, Bw, brow0, kb);
        }
        asm volatile("s_waitcnt vmcnt(2)" ::: "memory");
        __builtin_amdgcn_s_barrier();
        asm volatile("s_waitcnt lgkmcnt(0)" ::: "memory");
        __builtin_amdgcn_s_setprio(1);
        #pragma unroll
        for (int i = 0; i < 2; ++i)
            #pragma unroll
            for (int j = 0; j < 4; ++j) {
                acc[2 + i][j] = __builtin_amdgcn_mfma_f32_16x16x32_bf16(af2[i][0], bfr[j][0], acc[2 + i][j], 0, 0, 0);
                acc[2 + i][j] = __builtin_amdgcn_mfma_f32_16x16x32_bf16(af2[i][1], bfr[j][1], acc[2 + i][j], 0, 0, 0);
            }
        __builtin_amdgcn_s_setprio(0);
        __builtin_amdgcn_s_barrier();
    }
    asm volatile("s_waitcnt vmcnt(0)" ::: "memory");

    const int row00 = bx * 256 + wid_m * 64;
    const int col0 = by * 128 + wid_n * 64;
    #pragma unroll
    for (int i = 0; i < 4; ++i)
        #pragma unroll
        for (int j = 0; j < 4; ++j) {
            int c = col0 + j * 16 + fr;
            float bv = bias[c];
            #pragma unroll
            for (int r = 0; r < 4; ++r) {
                int row = row00 + i * 16 + fg * 4 + r;
                Cf[(size_t)row * 1024 + c] = acc[i][j][r] + bv;
            }
        }
}

// ---------------- Flash attention v5 (r13 measured-best) + max3 tree ----------------
__global__ __launch_bounds__(512, 4) void attn_fwd5(const unsigned short* __restrict__ Qp,
                                                    const unsigned short* __restrict__ Kp,
                                                    const unsigned short* __restrict__ VTg,
                                                    unsigned short* __restrict__ ctx)
{
    __shared__ unsigned short Ks[64][68];
    __shared__ unsigned short Vt[64][68];
    __shared__ unsigned short Ps[8][16][68];

    const int lin = blockIdx.x;
    const int xcd = lin & 7;
    const int w = lin >> 3;
    const int bh = xcd * 8 + (w & 7);     // XCD owns 8 complete heads
    const int j = 15 - (w >> 3);          // heavy blocks first
    const int b = bh >> 4, h = bh & 15;
    const int tid = threadIdx.x, lane = tid & 63, wid = tid >> 6;
    const int fr = lane & 15, fg = lane >> 4;

    const unsigned short* Qh  = Qp  + (size_t)bh * (S_ * DH_);
    const unsigned short* Kh  = Kp  + (size_t)bh * (S_ * DH_);
    const unsigned short* VTh = VTg + (size_t)bh * (DH_ * S_);

    const int srow = tid >> 3;
    const int scol = (tid & 7) * 8;

    bf16x8 ones;
    #pragma unroll
    for (int i = 0; i < 8; ++i) ones[i] = (__bf16)1.0f;

    const int q0 = j * 128;
    const int ntiles = 2 * (j + 1);
    const int rbase = q0 + wid * 16;
    const int qg = rbase + fr;

    bf16x8 qf[2];
    #pragma unroll
    for (int ks = 0; ks < 2; ++ks)
        qf[ks] = *(const bf16x8*)&Qh[(size_t)qg * 64 + ks * 32 + 8 * fg];

    f32x4 oacc[4] = {};
    float m_run = -3.0e38f, l_run = 0.0f;

    int4 kreg = *(const int4*)&Kh[(size_t)srow * 64 + scol];
    int4 vreg = *(const int4*)&VTh[(size_t)srow * 2048 + scol];

    for (int kt = 0; kt < ntiles; ++kt) {
        const int kv0 = kt * 64;
        __syncthreads();
        *(int4*)&Ks[srow][scol] = kreg;
        *(int4*)&Vt[srow][scol] = vreg;
        if (kt + 1 < ntiles) {
            const int kv1 = kv0 + 64;
            kreg = *(const int4*)&Kh[(size_t)(kv1 + srow) * 64 + scol];
            vreg = *(const int4*)&VTh[(size_t)srow * 2048 + kv1 + scol];
        }
        __syncthreads();

        if (kv0 > rbase + 15) continue;

        f32x4 sacc[4] = {};
        #pragma unroll
        for (int nt = 0; nt < 4; ++nt)
            #pragma unroll
            for (int ks = 0; ks < 2; ++ks) {
                bf16x8 kf = *(const bf16x8*)&Ks[nt * 16 + fr][ks * 32 + 8 * fg];
                sacc[nt] = __builtin_amdgcn_mfma_f32_16x16x32_bf16(kf, qf[ks], sacc[nt], 0, 0, 0);
            }

        if (kv0 + 63 > rbase) {
            const int kbase = kv0 + fg * 4;
            #pragma unroll
            for (int nt = 0; nt < 4; ++nt)
                #pragma unroll
                for (int r = 0; r < 4; ++r)
                    if (kbase + nt * 16 + r > qg) sacc[nt][r] = -3.0e38f;
        }

        // row max over 16 in-lane values: max3 tree + 2 cross-fg shuffles
        float ta = max3f(sacc[0][0], sacc[0][1], sacc[0][2]);
        float tb = max3f(sacc[0][3], sacc[1][0], sacc[1][1]);
        float tc = max3f(sacc[1][2], sacc[1][3], sacc[2][0]);
        float td = max3f(sacc[2][1], sacc[2][2], sacc[2][3]);
        float te = max3f(sacc[3][0], sacc[3][1], sacc[3][2]);
        float vm = fmaxf(max3f(ta, tb, sacc[3][3]), max3f(tc, td, te));
        vm = fmaxf(vm, __shfl_xor(vm, 16));
        vm = fmaxf(vm, __shfl_xor(vm, 32));

        if (!__all(vm - m_run <= 8.0f)) {
            const float mn = fmaxf(m_run, vm);
            const float alpha = exp2f(m_run - mn);
            m_run = mn;
            l_run *= alpha;
            #pragma unroll
            for (int dt = 0; dt < 4; ++dt)
                #pragma unroll
                for (int r = 0; r < 4; ++r) oacc[dt][r] *= alpha;
        }

        #pragma unroll
        for (int nt = 0; nt < 4; ++nt) {
            bf16x4 t;
            t[0] = (__bf16)exp2f(sacc[nt][0] - m_run);
            t[1] = (__bf16)exp2f(sacc[nt][1] - m_run);
            t[2] = (__bf16)exp2f(sacc[nt][2] - m_run);
            t[3] = (__bf16)exp2f(sacc[nt][3] - m_run);
            *(bf16x4*)&Ps[wid][fr][nt * 16 + fg * 4] = t;
        }
        asm volatile("s_waitcnt lgkmcnt(0)" ::: "memory");

        bf16x8 pb[2];
        #pragma unroll
        for (int ks = 0; ks < 2; ++ks)
            pb[ks] = *(const bf16x8*)&Ps[wid][fr][ks * 32 + 8 * fg];

        f32x4 racc = {};
        #pragma unroll
        for (int ks = 0; ks < 2; ++ks)
            racc = __builtin_amdgcn_mfma_f32_16x16x32_bf16(ones, pb[ks], racc, 0, 0, 0);
        #pragma unroll
        for (int dt = 0; dt < 4; ++dt)
            #pragma unroll
            for (int ks = 0; ks < 2; ++ks) {
                bf16x8 vf = *(const bf16x8*)&Vt[dt * 16 + fr][ks * 32 + 8 * fg];
                oacc[dt] = __builtin_amdgcn_mfma_f32_16x16x32_bf16(vf, pb[ks], oacc[dt], 0, 0, 0);
            }
        l_run += racc[0];
    }

    const float linv = 1.0f / l_run;
    unsigned short* cb = &ctx[(size_t)(b * 2048 + qg) * 1024 + h * 64];
    #pragma unroll
    for (int dt = 0; dt < 4; ++dt) {
        unsigned int w0 = f2bf(oacc[dt][0] * linv) | (f2bf(oacc[dt][1] * linv) << 16);
        unsigned int w1 = f2bf(oacc[dt][2] * linv) | (f2bf(oacc[dt][3] * linv) << 16);
        *(uint2*)&cb[dt * 16 + fg * 4] = make_uint2(w0, w1);
    }
}

extern "C" void kernel_launch(void* const* d_in, const int* in_sizes, int n_in,
                              void* d_out, int out_size, void* d_ws, size_t ws_size,
                              hipStream_t stream)
{
    const float* q  = (const float*)d_in[0];
    const float* k  = (const float*)d_in[1];
    const float* v  = (const float*)d_in[2];
    const float* Wq = (const float*)d_in[4];
    const float* bq = (const float*)d_in[5];
    const float* Wk = (const float*)d_in[6];
    const float* bk = (const float*)d_in[7];
    const float* Wv = (const float*)d_in[8];
    const float* bv = (const float*)d_in[9];
    const float* Wo = (const float*)d_in[10];
    const float* bo = (const float*)d_in[11];
    float* out = (float*)d_out;

    unsigned short* Wcat = (unsigned short*)d_ws;          // [Wq;Wk;Wv;Wo] bf16
    unsigned short* actb = Wcat + 4 * 1048576;             // [qb;kb;vb] bf16
    unsigned short* Qp   = actb + 3 * (size_t)NE_;
    unsigned short* Kp   = Qp + NE_;
    unsigned short* VTp  = Kp + NE_;                       // V in [B,H,DH,S]
    unsigned short* Ctx  = VTp + NE_;

    const float SCQ = 0.045084220027780106f;  // log2(e)/sqrt(D)

    dim3 blk(256);
    cvt_all<<<dim3(8192, 7), blk, 0, stream>>>(Wq, Wk, Wv, Wo, q, k, v, Wcat, actb);

    gemm_qkv8<<<dim3(384), dim3(512), 0, stream>>>(actb, Wcat, bq, bk, bv, Qp, Kp, VTp, SCQ);

    attn_fwd5<<<dim3(1024), dim3(512), 0, stream>>>(Qp, Kp, VTp, Ctx);

    gemm_o2<<<dim3(256), dim3(512), 0, stream>>>(Ctx, Wcat + 3 * 1048576, bo, out);
}